// Round 6
// baseline (255.557 us; speedup 1.0000x reference)
//
#include <hip/hip_runtime.h>
#include <hip/hip_bf16.h>
#include <math.h>

#define DMODEL 512
#define NHEAD  8
#define DHEAD  64

typedef __attribute__((ext_vector_type(8))) short bf16x8;
typedef __attribute__((ext_vector_type(4))) float f32x4;
typedef __attribute__((ext_vector_type(4))) short short4v;

static __device__ inline short f2bf(float f) {
    __hip_bfloat16 h = __float2bfloat16(f);
    return *reinterpret_cast<short*>(&h);
}

#define GLOAD_LDS16(gp, lp)                                                      \
    __builtin_amdgcn_global_load_lds(                                            \
        (const __attribute__((address_space(1))) unsigned int*)(gp),             \
        (__attribute__((address_space(3))) unsigned int*)(lp), 16, 0, 0)

// ============================ weight fp32 -> bf16 convert ============================
struct CvtArgs {
    const float* src[10];
    short*       dst[10];
    int          n[10];
};

__global__ __launch_bounds__(256) void cvt_kernel(CvtArgs args) {
    int t = blockIdx.y;
    int idx = (blockIdx.x * 256 + threadIdx.x) * 8;
    if (idx >= args.n[t]) return;
    const float* s = args.src[t] + idx;
    float4 a = *(const float4*)s;
    float4 b = *(const float4*)(s + 4);
    bf16x8 o;
    o[0] = f2bf(a.x); o[1] = f2bf(a.y); o[2] = f2bf(a.z); o[3] = f2bf(a.w);
    o[4] = f2bf(b.x); o[5] = f2bf(b.y); o[6] = f2bf(b.z); o[7] = f2bf(b.w);
    *(bf16x8*)(args.dst[t] + idx) = o;
}

// ============================ LayerNorm (+ optional row converts) ============================
// 256 threads = 4 waves = 4 rows. LN(X)->Y16; optionally also convert rows of
// C1src->C1dst and C2src->C2dst (straight fp32->bf16, same row indexing).
__global__ __launch_bounds__(256) void ln_kernel(const float* __restrict__ X,
                                                 const float* __restrict__ gam,
                                                 const float* __restrict__ bet,
                                                 short* __restrict__ Y,
                                                 const float* __restrict__ C1s,
                                                 short* __restrict__ C1d,
                                                 const float* __restrict__ C2s,
                                                 short* __restrict__ C2d) {
    int row = blockIdx.x * 4 + (threadIdx.x >> 6);
    int tid = threadIdx.x & 63;
    const float* x = X + (size_t)row * DMODEL;
    float4 a = *(const float4*)(x + tid * 4);
    float4 b = *(const float4*)(x + 256 + tid * 4);
    float sum = a.x + a.y + a.z + a.w + b.x + b.y + b.z + b.w;
    float sq  = a.x*a.x + a.y*a.y + a.z*a.z + a.w*a.w
              + b.x*b.x + b.y*b.y + b.z*b.z + b.w*b.w;
#pragma unroll
    for (int off = 1; off < 64; off <<= 1) {
        sum += __shfl_xor(sum, off);
        sq  += __shfl_xor(sq, off);
    }
    float mu  = sum * (1.0f / DMODEL);
    float var = sq * (1.0f / DMODEL) - mu * mu;
    float r   = rsqrtf(var + 1e-6f);

    float4 g1 = *(const float4*)(gam + tid * 4);
    float4 c1 = *(const float4*)(bet + tid * 4);
    float4 g2 = *(const float4*)(gam + 256 + tid * 4);
    float4 c2 = *(const float4*)(bet + 256 + tid * 4);
    short4v y1, y2;
    y1.x = f2bf((a.x - mu) * r * g1.x + c1.x);
    y1.y = f2bf((a.y - mu) * r * g1.y + c1.y);
    y1.z = f2bf((a.z - mu) * r * g1.z + c1.z);
    y1.w = f2bf((a.w - mu) * r * g1.w + c1.w);
    y2.x = f2bf((b.x - mu) * r * g2.x + c2.x);
    y2.y = f2bf((b.y - mu) * r * g2.y + c2.y);
    y2.z = f2bf((b.z - mu) * r * g2.z + c2.z);
    y2.w = f2bf((b.w - mu) * r * g2.w + c2.w);
    short* y = Y + (size_t)row * DMODEL;
    *(short4v*)(y + tid * 4)       = y1;
    *(short4v*)(y + 256 + tid * 4) = y2;

    if (C1s) {
        // X == C1s rows (dec): reuse a/b
        short4v d1, d2;
        d1.x = f2bf(a.x); d1.y = f2bf(a.y); d1.z = f2bf(a.z); d1.w = f2bf(a.w);
        d2.x = f2bf(b.x); d2.y = f2bf(b.y); d2.z = f2bf(b.z); d2.w = f2bf(b.w);
        short* d = C1d + (size_t)row * DMODEL;
        *(short4v*)(d + tid * 4)       = d1;
        *(short4v*)(d + 256 + tid * 4) = d2;
    }
    if (C2s) {
        const float* e = C2s + (size_t)row * DMODEL;
        float4 ea = *(const float4*)(e + tid * 4);
        float4 eb = *(const float4*)(e + 256 + tid * 4);
        short4v d1, d2;
        d1.x = f2bf(ea.x); d1.y = f2bf(ea.y); d1.z = f2bf(ea.z); d1.w = f2bf(ea.w);
        d2.x = f2bf(eb.x); d2.y = f2bf(eb.y); d2.z = f2bf(eb.z); d2.w = f2bf(eb.w);
        short* d = C2d + (size_t)row * DMODEL;
        *(short4v*)(d + tid * 4)       = d1;
        *(short4v*)(d + 256 + tid * 4) = d2;
    }
}

// ============================ bf16 MFMA GEMM (multi-job, dbuf) ============================
// Per job: C[M,N] = scale*(A[M,K] @ W[N,K]^T) [+bias f32][+resid f32][relu]
// 256 threads = 4 waves (2x2); block tile 64x64, wave tile 32x32, BK=64.
// Double-buffered LDS: one barrier/iter, loads for k+1 fly during compute of k.
struct GJobs {
    const short* A[3];
    const short* W[3];
    const float* bias[3];
    const float* resid[3];
    void*        C[3];
    int M[3], N[3], K[3];
    float scale[3];
    int relu[3], obf[3], nblk[3];
};

__global__ __launch_bounds__(256) void gemm_bf16(GJobs jb) {
    __shared__ short As[2][64 * 64];   // 2 x 8 KB
    __shared__ short Bs[2][64 * 64];   // 2 x 8 KB

    int bid = blockIdx.x, j = 0;
    while (j < 2 && bid >= jb.nblk[j]) { bid -= jb.nblk[j]; ++j; }
    const short* __restrict__ A = jb.A[j];
    const short* __restrict__ W = jb.W[j];
    const int N = jb.N[j], K = jb.K[j];
    const int nbx = N >> 6;
    const int tn = (bid % nbx) * 64;
    const int tm = (bid / nbx) * 64;

    const int tid  = threadIdx.x;
    const int w    = tid >> 6;
    const int l    = tid & 63;
    const int lq   = l & 15;
    const int g    = l >> 4;
    const int wm   = (w >> 1) * 32;
    const int wn   = (w & 1) * 32;
    const int lrow = l >> 3;
    const int lsl  = l & 7;

    f32x4 acc[2][2];
#pragma unroll
    for (int i = 0; i < 2; ++i)
#pragma unroll
        for (int jj = 0; jj < 2; ++jj)
            acc[i][jj] = (f32x4){0.f, 0.f, 0.f, 0.f};

    // stage(buf, k0): global slot kbg = lsl ^ (row&7); LDS slot = lsl.
#define GSTAGE(buf, koff)                                                        \
    do {                                                                         \
        _Pragma("unroll")                                                        \
        for (int i_ = 0; i_ < 2; ++i_) {                                         \
            int row_ = i_ * 32 + w * 8 + lrow;                                   \
            int slot_ = lsl ^ (row_ & 7);                                        \
            GLOAD_LDS16(A + (size_t)(tm + row_) * K + (koff) + slot_ * 8,        \
                        As[buf] + i_ * 2048 + w * 512);                          \
            GLOAD_LDS16(W + (size_t)(tn + row_) * K + (koff) + slot_ * 8,        \
                        Bs[buf] + i_ * 2048 + w * 512);                          \
        }                                                                        \
    } while (0)

    GSTAGE(0, 0);
    int buf = 0;
#pragma unroll 1
    for (int k0 = 0; k0 < K; k0 += 64, buf ^= 1) {
        __syncthreads();                       // buf's loads complete here
        if (k0 + 64 < K) GSTAGE(buf ^ 1, k0 + 64);
#pragma unroll
        for (int ks = 0; ks < 2; ++ks) {
            const int sl = ((ks * 4 + g) ^ (lq & 7)) * 8;
            bf16x8 af[2], bfv[2];
#pragma unroll
            for (int i = 0; i < 2; ++i) {
                af[i]  = *(const bf16x8*)&As[buf][(wm + i * 16 + lq) * 64 + sl];
                bfv[i] = *(const bf16x8*)&Bs[buf][(wn + i * 16 + lq) * 64 + sl];
            }
#pragma unroll
            for (int i = 0; i < 2; ++i)
#pragma unroll
                for (int jj = 0; jj < 2; ++jj)
                    acc[i][jj] = __builtin_amdgcn_mfma_f32_16x16x32_bf16(
                        af[i], bfv[jj], acc[i][jj], 0, 0, 0);
        }
    }
#undef GSTAGE

    const float* bias  = jb.bias[j];
    const float* resid = jb.resid[j];
    const float scale  = jb.scale[j];
    const int relu = jb.relu[j], obf = jb.obf[j];
#pragma unroll
    for (int i = 0; i < 2; ++i) {
#pragma unroll
        for (int r = 0; r < 4; ++r) {
            int row = tm + wm + i * 16 + g * 4 + r;
#pragma unroll
            for (int jj = 0; jj < 2; ++jj) {
                int col = tn + wn + jj * 16 + lq;
                float v = acc[i][jj][r] * scale;
                if (bias)  v += bias[col];
                if (resid) v += resid[(size_t)row * N + col];
                if (relu)  v = fmaxf(v, 0.f);
                if (obf) ((short*)jb.C[j])[(size_t)row * N + col] = f2bf(v);
                else     ((float*)jb.C[j])[(size_t)row * N + col] = v;
            }
        }
    }
}

// ============================ MFMA flash attention (shuffle-free) ============================
// Block = one 64-query band (4 waves x 16 q-rows) -> uniform nkt per block
// (no barrier divergence, no stale staging). Causal load balance via
// complementary band pairing across the two bh halves.
__global__ __launch_bounds__(256) void attn_mfma_kernel(
        const short* __restrict__ Q, const short* __restrict__ K,
        const short* __restrict__ V, short* __restrict__ O,
        int Lq, int Lk, int causal, int qs, int kvs) {
    __shared__ short Kt[64 * 64];        // [key][d] swizzled rows, 8 KB
    __shared__ short Vt[64][72];         // [d][key], 9 KB
    __shared__ short Pb[4][16][72];      // per-wave P tile [q][key], 9 KB

    const int tid  = threadIdx.x;
    const int wave = tid >> 6;
    const int lane = tid & 63;
    const int lq   = lane & 15;
    const int g    = lane >> 4;
    const int bh   = blockIdx.y;
    const int b = bh >> 3, h = bh & 7;
    const int band = causal ? ((bh < 16) ? (int)blockIdx.x : (15 - (int)blockIdx.x))
                            : (int)blockIdx.x;
    const int qt = band * 4 + wave;
    const int q0 = qt * 16;
    const float NEG = -__builtin_inff();

    size_t qoff = (size_t)(b * Lq + q0 + lq) * qs + h * DHEAD;
    bf16x8 qf0 = *(const bf16x8*)(Q + qoff + g * 8);
    bf16x8 qf1 = *(const bf16x8*)(Q + qoff + 32 + g * 8);

    f32x4 o[4] = {{0,0,0,0},{0,0,0,0},{0,0,0,0},{0,0,0,0}};
    f32x4 lacc = {0.f, 0.f, 0.f, 0.f};

    bf16x8 ones;
    {
        short ov = (lq == 0) ? (short)0x3F80 : (short)0;
#pragma unroll
        for (int i = 0; i < 8; ++i) ones[i] = ov;
    }

    const int nkt = causal ? (band + 1) : (Lk >> 6);   // uniform across block
    const int lrow = lane >> 3;
    const int lsl  = lane & 7;
    const int va = tid & 31;
    const int vd = (tid >> 5) * 8;

#pragma unroll 1
    for (int kt = 0; kt < nkt; ++kt) {
        __syncthreads();
#pragma unroll
        for (int i = 0; i < 2; ++i) {
            int row = i * 32 + wave * 8 + lrow;
            int slot = lsl ^ (row & 7);
            GLOAD_LDS16(K + (size_t)(b * Lk + kt * 64 + row) * kvs + h * DHEAD + slot * 8,
                        Kt + i * 2048 + wave * 512);
        }
        {
            size_t gb = (size_t)(b * Lk + kt * 64 + 2 * va) * kvs + h * DHEAD + vd;
            bf16x8 v0 = *(const bf16x8*)(V + gb);
            bf16x8 v1 = *(const bf16x8*)(V + gb + kvs);
#pragma unroll
            for (int i = 0; i < 8; ++i) {
                unsigned p = (unsigned short)v0[i] | ((unsigned)(unsigned short)v1[i] << 16);
                *(unsigned*)&Vt[vd + i][2 * va] = p;
            }
        }
        __syncthreads();

        // ---- S^T = K Q^T ----
        f32x4 s[4];
#pragma unroll
        for (int sub = 0; sub < 4; ++sub) {
            int rr = sub * 16 + lq;
            const int sl0 = ((0 + g) ^ (lq & 7)) * 8;
            const int sl1 = ((4 + g) ^ (lq & 7)) * 8;
            bf16x8 kf0 = *(const bf16x8*)&Kt[rr * 64 + sl0];
            bf16x8 kf1 = *(const bf16x8*)&Kt[rr * 64 + sl1];
            f32x4 a = {0.f, 0.f, 0.f, 0.f};
            a = __builtin_amdgcn_mfma_f32_16x16x32_bf16(kf0, qf0, a, 0, 0, 0);
            a = __builtin_amdgcn_mfma_f32_16x16x32_bf16(kf1, qf1, a, 0, 0, 0);
            s[sub] = a;
        }
        if (causal && kt == nkt - 1) {
            int qg = q0 + lq;
#pragma unroll
            for (int sub = 0; sub < 4; ++sub) {
#pragma unroll
                for (int r = 0; r < 4; ++r) {
                    int kg = kt * 64 + sub * 16 + g * 4 + r;
                    if (kg > qg) s[sub][r] = NEG;
                }
            }
        }

        // ---- exp (no max subtraction; clamped) + packed P write ----
#pragma unroll
        for (int sub = 0; sub < 4; ++sub) {
            short4v p4;
            p4.x = f2bf(__expf(fminf(s[sub][0], 60.f)));
            p4.y = f2bf(__expf(fminf(s[sub][1], 60.f)));
            p4.z = f2bf(__expf(fminf(s[sub][2], 60.f)));
            p4.w = f2bf(__expf(fminf(s[sub][3], 60.f)));
            *(short4v*)&Pb[wave][lq][sub * 16 + g * 4] = p4;
        }
        bf16x8 pf0 = *(const bf16x8*)&Pb[wave][lq][g * 8];
        bf16x8 pf1 = *(const bf16x8*)&Pb[wave][lq][32 + g * 8];

        // ---- O += P V ; l += P @ ones ----
#pragma unroll
        for (int dc = 0; dc < 4; ++dc) {
            bf16x8 vf0 = *(const bf16x8*)&Vt[dc * 16 + lq][g * 8];
            bf16x8 vf1 = *(const bf16x8*)&Vt[dc * 16 + lq][32 + g * 8];
            o[dc] = __builtin_amdgcn_mfma_f32_16x16x32_bf16(pf0, vf0, o[dc], 0, 0, 0);
            o[dc] = __builtin_amdgcn_mfma_f32_16x16x32_bf16(pf1, vf1, o[dc], 0, 0, 0);
        }
        lacc = __builtin_amdgcn_mfma_f32_16x16x32_bf16(pf0, ones, lacc, 0, 0, 0);
        lacc = __builtin_amdgcn_mfma_f32_16x16x32_bf16(pf1, ones, lacc, 0, 0, 0);
    }

#pragma unroll
    for (int r = 0; r < 4; ++r) {
        float lr = __shfl(lacc[r], g << 4);
        float inv = 1.f / lr;
        size_t ob = (size_t)(b * Lq + q0 + g * 4 + r) * qs + h * DHEAD + lq;
        O[ob + 0]  = f2bf(o[0][r] * inv);
        O[ob + 16] = f2bf(o[1][r] * inv);
        O[ob + 32] = f2bf(o[2][r] * inv);
        O[ob + 48] = f2bf(o[3][r] * inv);
    }
}

// ============================ Launch ============================
static void launch_gemm(GJobs& jb, int njobs, hipStream_t stream) {
    int total = 0;
    for (int i = 0; i < 3; ++i) { if (i >= njobs) jb.nblk[i] = 0; total += jb.nblk[i]; }
    gemm_bf16<<<total, 256, 0, stream>>>(jb);
}

extern "C" void kernel_launch(void* const* d_in, const int* in_sizes, int n_in,
                              void* d_out, int out_size, void* d_ws, size_t ws_size,
                              hipStream_t stream) {
    const float* dec       = (const float*)d_in[0];
    const float* enc       = (const float*)d_in[1];
    const float* slf_Wq    = (const float*)d_in[3];
    const float* slf_Wk    = (const float*)d_in[4];
    const float* slf_Wv    = (const float*)d_in[5];
    const float* slf_Wfc   = (const float*)d_in[6];
    const float* slf_ln_g  = (const float*)d_in[7];
    const float* slf_ln_b  = (const float*)d_in[8];
    const float* enc_Wq    = (const float*)d_in[9];
    const float* enc_Wk    = (const float*)d_in[10];
    const float* enc_Wv    = (const float*)d_in[11];
    const float* enc_Wfc   = (const float*)d_in[12];
    const float* enc_ln_g  = (const float*)d_in[13];
    const float* enc_ln_b  = (const float*)d_in[14];
    const float* ffn_W1    = (const float*)d_in[15];
    const float* ffn_b1    = (const float*)d_in[16];
    const float* ffn_W2    = (const float*)d_in[17];
    const float* ffn_b2    = (const float*)d_in[18];
    const float* ffn_ln_g  = (const float*)d_in[19];
    const float* ffn_ln_b  = (const float*)d_in[20];
    float* out = (float*)d_out;

    const int Bb = 4, L = 1024, M = Bb * L;
    const size_t NE = (size_t)M * DMODEL;          // 2M
    const int WQN = NHEAD * DHEAD * DMODEL;        // 262144
    float* ws = (float*)d_ws;
    float* x1 = ws;
    float* x2 = ws + NE;
    short* kv16e = (short*)x2;     // alias: kv16e consumed (attn2) before x2 written
    short* sb = (short*)(ws + 2 * NE);
    short* dec16 = sb;               sb += NE;
    short* enc16 = sb;               sb += NE;
    short* qn16  = sb;               sb += NE;
    short* q16   = sb;               sb += NE;
    short* ao16  = sb;               sb += NE;
    short* kv16  = sb;               sb += 2 * NE;
    short* h16   = sb;               sb += NE / 2;
    short* wq_s  = sb;               sb += WQN;
    short* wkv_s = sb;               sb += 2 * WQN;
    short* wfc_s = sb;               sb += WQN;
    short* wq_e  = sb;               sb += WQN;
    short* wkv_e = sb;               sb += 2 * WQN;
    short* wfc_e = sb;               sb += WQN;
    short* w1_16 = sb;               sb += 256 * DMODEL;
    short* w2_16 = sb;               sb += DMODEL * 256;

    CvtArgs ca;
    ca.src[0] = slf_Wq;  ca.dst[0] = wq_s;          ca.n[0] = WQN;
    ca.src[1] = slf_Wk;  ca.dst[1] = wkv_s;         ca.n[1] = WQN;
    ca.src[2] = slf_Wv;  ca.dst[2] = wkv_s + WQN;   ca.n[2] = WQN;
    ca.src[3] = slf_Wfc; ca.dst[3] = wfc_s;         ca.n[3] = WQN;
    ca.src[4] = enc_Wq;  ca.dst[4] = wq_e;          ca.n[4] = WQN;
    ca.src[5] = enc_Wk;  ca.dst[5] = wkv_e;         ca.n[5] = WQN;
    ca.src[6] = enc_Wv;  ca.dst[6] = wkv_e + WQN;   ca.n[6] = WQN;
    ca.src[7] = enc_Wfc; ca.dst[7] = wfc_e;         ca.n[7] = WQN;
    ca.src[8] = ffn_W1;  ca.dst[8] = w1_16;         ca.n[8] = 256 * DMODEL;
    ca.src[9] = ffn_W2;  ca.dst[9] = w2_16;         ca.n[9] = DMODEL * 256;
    cvt_kernel<<<dim3(128, 10), 256, 0, stream>>>(ca);

    dim3 attn_grid(L / 64, Bb * NHEAD);
    const int NB512  = (M / 64) * (512 / 64);    // 512
    const int NB1024 = (M / 64) * (1024 / 64);   // 1024
    const int NB256  = (M / 64) * (256 / 64);    // 256

    // ---- LN1 (+ dec/enc bf16 converts) + fused {Q_self, KV_self, KV_cross} ----
    ln_kernel<<<M / 4, 256, 0, stream>>>(dec, slf_ln_g, slf_ln_b, qn16,
                                         dec, dec16, enc, enc16);
    {
        GJobs jb = {};
        jb.A[0] = qn16;  jb.W[0] = wq_s;  jb.C[0] = q16;
        jb.M[0] = M; jb.N[0] = 512;  jb.K[0] = 512; jb.scale[0] = 0.125f;
        jb.obf[0] = 1; jb.nblk[0] = NB512;
        jb.A[1] = dec16; jb.W[1] = wkv_s; jb.C[1] = kv16;
        jb.M[1] = M; jb.N[1] = 1024; jb.K[1] = 512; jb.scale[1] = 1.f;
        jb.obf[1] = 1; jb.nblk[1] = NB1024;
        jb.A[2] = enc16; jb.W[2] = wkv_e; jb.C[2] = kv16e;
        jb.M[2] = M; jb.N[2] = 1024; jb.K[2] = 512; jb.scale[2] = 1.f;
        jb.obf[2] = 1; jb.nblk[2] = NB1024;
        launch_gemm(jb, 3, stream);
    }
    attn_mfma_kernel<<<attn_grid, 256, 0, stream>>>(q16, kv16, kv16 + 512, ao16,
                                                    L, L, 1, DMODEL, 1024);
    {
        GJobs jb = {};
        jb.A[0] = ao16; jb.W[0] = wfc_s; jb.resid[0] = dec; jb.C[0] = x1;
        jb.M[0] = M; jb.N[0] = 512; jb.K[0] = 512; jb.scale[0] = 1.f;
        jb.obf[0] = 0; jb.nblk[0] = NB512;
        launch_gemm(jb, 1, stream);
    }

    // ---- cross attention ----
    ln_kernel<<<M / 4, 256, 0, stream>>>(x1, enc_ln_g, enc_ln_b, qn16,
                                         nullptr, nullptr, nullptr, nullptr);
    {
        GJobs jb = {};
        jb.A[0] = qn16; jb.W[0] = wq_e; jb.C[0] = q16;
        jb.M[0] = M; jb.N[0] = 512; jb.K[0] = 512; jb.scale[0] = 0.125f;
        jb.obf[0] = 1; jb.nblk[0] = NB512;
        launch_gemm(jb, 1, stream);
    }
    attn_mfma_kernel<<<attn_grid, 256, 0, stream>>>(q16, kv16e, kv16e + 512, ao16,
                                                    L, L, 0, DMODEL, 1024);
    {
        GJobs jb = {};
        jb.A[0] = ao16; jb.W[0] = wfc_e; jb.resid[0] = x1; jb.C[0] = x2;
        jb.M[0] = M; jb.N[0] = 512; jb.K[0] = 512; jb.scale[0] = 1.f;
        jb.obf[0] = 0; jb.nblk[0] = NB512;
        launch_gemm(jb, 1, stream);
    }

    // ---- FFN ----
    ln_kernel<<<M / 4, 256, 0, stream>>>(x2, ffn_ln_g, ffn_ln_b, qn16,
                                         nullptr, nullptr, nullptr, nullptr);
    {
        GJobs jb = {};
        jb.A[0] = qn16; jb.W[0] = w1_16; jb.bias[0] = ffn_b1; jb.C[0] = h16;
        jb.M[0] = M; jb.N[0] = 256; jb.K[0] = 512; jb.scale[0] = 1.f;
        jb.relu[0] = 1; jb.obf[0] = 1; jb.nblk[0] = NB256;
        launch_gemm(jb, 1, stream);
    }
    {
        GJobs jb = {};
        jb.A[0] = h16; jb.W[0] = w2_16; jb.bias[0] = ffn_b2; jb.resid[0] = x2;
        jb.C[0] = out;
        jb.M[0] = M; jb.N[0] = 512; jb.K[0] = 256; jb.scale[0] = 1.f;
        jb.obf[0] = 0; jb.nblk[0] = NB512;
        launch_gemm(jb, 1, stream);
    }
}